// Round 7
// baseline (2901.835 us; speedup 1.0000x reference)
//
#include <hip/hip_runtime.h>

// SimpleRNN: VOCAB=32000, EMBED=256, HIDDEN=512, N=256, L=512
// out = h_512 (256x512 f32), h_{t+1} = tanh(h W_hh^T + b_hh + b_xh + emb[X] W_xh^T)
//
// Round-7: col-split pair structure -> 32 CUs active (vs 16).
//  Block b: pid = b & 15 (batch rows [16pid,16pid+16)), half = b >> 4 (out cols [256half,+256)).
//  Pair (pid,0) <-> (pid,1) exchange 8KB h-halves per step via L2 + agent-scope flags.
//  W slice per wave = 16kt x 2mt = 32 frags = 128 VGPR -> fully arch-register-resident.
//  Step: [phase A: own-half kt MFMAs] [import partner h-half] [barrier]
//        [phase B: partner kt MFMAs] [epilogue -> LDS + xch export] [barrier] [flag++].
//  Cooperative launch guarantees co-residency; bounded spin prevents hangs.

typedef _Float16 f16;
typedef f16 f16x8 __attribute__((ext_vector_type(8)));
typedef float f32x4 __attribute__((ext_vector_type(4)));
typedef unsigned short u16;

union U8 { uint4 u; f16x8 h; };
union U4 { uint2 u; f16 h[4]; };

// ---------------------------------------------------------------- preconv ---
// One frag = 64 lanes x 8 f16 (1KB). lane l supplies W[col][k]:
//   col = c16*16 + (l&15), k = kt*32 + (l>>4)*8 + j.
// mode 0 (W_xh, K=256): f = (w*4+nt)*8 + kt                  (round-6 exact)
// mode 1 (W_hh, K=512): f = c16*16 + kt, c16=0..31, kt=0..15 (new col-tile-major)
__global__ void preconv_kernel(const float* __restrict__ W, u16* __restrict__ dst,
                               int kstride, int mode) {
  int t = blockIdx.x * blockDim.x + threadIdx.x;
  int f = t >> 6, l = t & 63;
  int kt, c16;
  if (mode == 0) { kt = f & 7; c16 = f >> 3; }
  else           { kt = f & 15; c16 = f >> 4; }
  int col = c16 * 16 + (l & 15);
  int k   = kt * 32 + (l >> 4) * 8;
  const float* src = W + (size_t)col * kstride + k;
  float4 v0 = *(const float4*)src;
  float4 v1 = *(const float4*)(src + 4);
  U8 r;
  r.h = (f16x8){(f16)v0.x, (f16)v0.y, (f16)v0.z, (f16)v0.w,
                (f16)v1.x, (f16)v1.y, (f16)v1.z, (f16)v1.w};
  *(uint4*)(dst + (size_t)f * 512 + l * 8) = r.u;
}
// NOTE mode 0: f = (w*4+nt)*8 + kt == ((w*4+nt))*8 + kt, c16 = w*4+nt = f>>3 ✓ identical to round 6.

// ----------------------------------------------------------------- phaseA ---
// Round-6 exact. Grid 1024 = 16 bn x 64 bl. 512 thr, 8 waves. Writes
// xpf[t][cq][n][4] f16, cq = col>>2, n = batch row, biases folded.
__global__ __launch_bounds__(512, 2) void phaseA_kernel(
    const int* __restrict__ X, const float* __restrict__ emb,
    const u16* __restrict__ Wxf, const float* __restrict__ b_hh,
    const float* __restrict__ b_xh, u16* __restrict__ xpf) {
  __shared__ f16 A[128 * 256];  // 64 KB
  const int tid = threadIdx.x, w = tid >> 6, l = tid & 63;
  const int b = blockIdx.x, bn = b >> 6, bl = b & 63;
  const int lr = l & 15, lg = l >> 4;

  f16x8 wx[4][8];
#pragma unroll
  for (int mt = 0; mt < 4; ++mt)
#pragma unroll
    for (int kt = 0; kt < 8; ++kt) {
      U8 u; u.u = *(const uint4*)(Wxf + (size_t)((w * 4 + mt) * 8 + kt) * 512 + l * 8);
      wx[mt][kt] = u.h;
    }
  float bias[4][4];
#pragma unroll
  for (int mt = 0; mt < 4; ++mt)
#pragma unroll
    for (int r = 0; r < 4; ++r) {
      int c = w * 64 + mt * 16 + lg * 4 + r;
      bias[mt][r] = b_hh[c] + b_xh[c];
    }

  int xs[16];
  const int lseq = bl * 8 + w;
#pragma unroll
  for (int i = 0; i < 16; ++i) xs[i] = X[(bn * 16 + i) * 512 + lseq];
#pragma unroll
  for (int i = 0; i < 16; ++i) {
    float4 v = *(const float4*)(emb + (size_t)xs[i] * 256 + l * 4);
    U4 p; p.h[0] = (f16)v.x; p.h[1] = (f16)v.y; p.h[2] = (f16)v.z; p.h[3] = (f16)v.w;
    int row = w * 16 + i;
    *(uint2*)(&A[row * 256 + ((l * 4) ^ ((row & 7) << 3))]) = p.u;
  }
  __syncthreads();

#pragma unroll 1
  for (int nt = 0; nt < 8; ++nt) {
    f32x4 acc[4];
#pragma unroll
    for (int mt = 0; mt < 4; ++mt) acc[mt] = (f32x4){0.f, 0.f, 0.f, 0.f};
    const f16* Brow = &A[(nt * 16 + lr) * 256];
    const int sw = (lr & 7) << 3;
#pragma unroll
    for (int kt = 0; kt < 8; ++kt) {
      f16x8 bfr = *(const f16x8*)(Brow + ((kt * 32 + lg * 8) ^ sw));
#pragma unroll
      for (int mt = 0; mt < 4; ++mt)
        acc[mt] = __builtin_amdgcn_mfma_f32_16x16x32_f16(wx[mt][kt], bfr, acc[mt], 0, 0, 0);
    }
    const int t = bl * 8 + nt;
#pragma unroll
    for (int mt = 0; mt < 4; ++mt) {
      U4 p;
#pragma unroll
      for (int r = 0; r < 4; ++r) p.h[r] = (f16)(acc[mt][r] + bias[mt][r]);
      *(uint2*)(xpf + (size_t)t * 131072 + (w * 16 + mt * 4 + lg) * 1024
                    + (bn * 16 + lr) * 4) = p.u;
    }
  }
}

// ----------------------------------------------------------------- phaseB ---
// 32 blocks x 512 thr (cooperative). h[16][512] f16 dbuf in LDS (32 KB static),
// storage rule: h[row][col] at col ^ ((row&7)<<3). Wave w: own cols
// [256half + 32w, +32), mt=0,1. All W in VGPRs.
__global__ __launch_bounds__(512, 2) void phaseB_kernel(
    const u16* __restrict__ Whf, const u16* __restrict__ xpf,
    u16* __restrict__ xch, int* __restrict__ flags, float* __restrict__ out) {
  __shared__ f16 hb0[16][512];  // 16 KB (even-step read buffer)
  __shared__ f16 hb1[16][512];  // 16 KB
  const int tid = threadIdx.x, w = tid >> 6, l = tid & 63;
  const int bb = blockIdx.x, pid = bb & 15, half = bb >> 4;
  const int lr = l & 15, lg = l >> 4;
  const int asw = (lr & 7) << 3;
  const int ownb = half * 256, othb = 256 - ownb;

  // W slots: i<8 -> own-half kts (8half+i), i>=8 -> partner kts (8(1-half)+i-8).
  // All register indices STATIC; half only affects addresses.
  f16x8 wreg[16][2];
#pragma unroll
  for (int i = 0; i < 16; ++i) {
    const int ktg = (i < 8) ? (8 * half + i) : (8 * (1 - half) + (i - 8));
#pragma unroll
    for (int mt = 0; mt < 2; ++mt) {
      const int f = (half * 16 + w * 2 + mt) * 16 + ktg;
      U8 u; u.u = *(const uint4*)(Whf + (size_t)f * 512 + l * 8);
      wreg[i][mt] = u.h;
    }
  }
  { // zero hb0 (t=0 reads both halves as h_0 = 0); hb1 fully written before read
    float* hz = (float*)hb0;
#pragma unroll
    for (int i = 0; i < 8; ++i) hz[i * 512 + tid] = 0.f;
  }
  __syncthreads();

  // invariants
  const u16* xpb = xpf + (size_t)(half * 64 + w * 8 + lg) * 1024 + (pid * 16 + lr) * 4;
  int* const myflag = flags + pid * 2 + half;
  int* const pflag  = flags + pid * 2 + (1 - half);
  // xch[par][pid][half][row][col'] f16: base = ((par*16+pid)*2+half)*4096
  u16* const xo0 = xch + ((size_t)(0 * 16 + pid) * 2 + half) * 4096;       // export, parity 0
  u16* const xo1 = xch + ((size_t)(1 * 16 + pid) * 2 + half) * 4096;       // export, parity 1
  const u16* const xi0 = xch + ((size_t)(0 * 16 + pid) * 2 + (1 - half)) * 4096;  // import, par 0
  const u16* const xi1 = xch + ((size_t)(1 * 16 + pid) * 2 + (1 - half)) * 4096;  // import, par 1
  const int irow = tid >> 5, icol = othb + (tid & 31) * 8;   // import slice mapping
  const int ioff = (irow * 512) + (icol ^ ((irow & 7) << 3));

#define STEP(T, HC, HN, XPc, XPn, XIN, XOUT)                                      \
  do {                                                                            \
    { /* prefetch xp for step T+1 (clamped, in-bounds) */                         \
      const int tn = ((T) + 1 < 512) ? ((T) + 1) : 511;                           \
      const u16* p = xpb + (size_t)tn * 131072;                                   \
      XPn[0] = *(const uint2*)(p);                                                \
      XPn[1] = *(const uint2*)(p + 4096);                                         \
    }                                                                             \
    f32x4 acc0 = (f32x4){0.f, 0.f, 0.f, 0.f};                                     \
    f32x4 acc1 = (f32x4){0.f, 0.f, 0.f, 0.f};                                     \
    _Pragma("unroll")                             /* phase A: own-half kts */     \
    for (int i = 0; i < 8; ++i) {                                                 \
      f16x8 hf = *(const f16x8*)(&HC[lr][(ownb + i * 32 + lg * 8) ^ asw]);        \
      acc0 = __builtin_amdgcn_mfma_f32_16x16x32_f16(wreg[i][0], hf, acc0, 0, 0, 0); \
      acc1 = __builtin_amdgcn_mfma_f32_16x16x32_f16(wreg[i][1], hf, acc1, 0, 0, 0); \
    }                                                                             \
    if ((T) > 0) { /* import partner half of h_T into HC */                       \
      int spins = 0;                                                              \
      while (__hip_atomic_load(pflag, __ATOMIC_ACQUIRE,                           \
                               __HIP_MEMORY_SCOPE_AGENT) < (T)) {                 \
        if (++spins > (1 << 22)) break;                                           \
      }                                                                           \
      U8 v; v.u = *(const uint4*)(XIN + tid * 8);                                 \
      *(uint4*)(&((f16*)HC)[ioff]) = v.u;                                         \
    }                                                                             \
    __syncthreads();  /* import visible to all waves */                           \
    _Pragma("unroll")                             /* phase B: partner kts */      \
    for (int i = 0; i < 8; ++i) {                                                 \
      f16x8 hf = *(const f16x8*)(&HC[lr][(othb + i * 32 + lg * 8) ^ asw]);        \
      acc0 = __builtin_amdgcn_mfma_f32_16x16x32_f16(wreg[8 + i][0], hf, acc0, 0, 0, 0); \
      acc1 = __builtin_amdgcn_mfma_f32_16x16x32_f16(wreg[8 + i][1], hf, acc1, 0, 0, 0); \
    }                                                                             \
    { /* epilogue: tanh -> HN own half + xch export */                            \
      u16* xc = XOUT + lr * 256 + w * 32 + lg * 4;                                \
      U4 px0; px0.u = XPc[0];                                                     \
      U4 o0;                                                                      \
      _Pragma("unroll")                                                           \
      for (int r = 0; r < 4; ++r) {                                               \
        float z = acc0[r] + (float)px0.h[r];                                      \
        float e = exp2f(z * 2.885390081777927f);                                  \
        o0.h[r] = (f16)(1.0f - 2.0f * __builtin_amdgcn_rcpf(e + 1.0f));           \
      }                                                                           \
      *(uint2*)(&HN[lr][(ownb + w * 32 + lg * 4) ^ asw]) = o0.u;                  \
      *(uint2*)(xc) = o0.u;                                                       \
      U4 px1; px1.u = XPc[1];                                                     \
      U4 o1;                                                                      \
      _Pragma("unroll")                                                           \
      for (int r = 0; r < 4; ++r) {                                               \
        float z = acc1[r] + (float)px1.h[r];                                      \
        float e = exp2f(z * 2.885390081777927f);                                  \
        o1.h[r] = (f16)(1.0f - 2.0f * __builtin_amdgcn_rcpf(e + 1.0f));           \
      }                                                                           \
      *(uint2*)(&HN[lr][(ownb + w * 32 + 16 + lg * 4) ^ asw]) = o1.u;             \
      *(uint2*)(xc + 16) = o1.u;                                                  \
    }                                                                             \
    asm volatile("s_waitcnt vmcnt(0)" ::: "memory"); /* export drained to L2 */   \
    __syncthreads();  /* all waves' HN writes + exports done */                   \
    if (tid == 0)                                                                 \
      __hip_atomic_store(myflag, (T) + 1, __ATOMIC_RELEASE,                       \
                         __HIP_MEMORY_SCOPE_AGENT);                               \
  } while (0)

  uint2 xpA[2], xpB[2];
  xpA[0] = *(const uint2*)(xpb);
  xpA[1] = *(const uint2*)(xpb + 4096);

#pragma unroll 1
  for (int t2 = 0; t2 < 256; ++t2) {
    const int t = t2 * 2;
    STEP(t,     hb0, hb1, xpA, xpB, xi0, xo1);  // even: read hb0/par0, write hb1/par1
    STEP(t + 1, hb1, hb0, xpB, xpA, xi1, xo0);  // odd : read hb1/par1, write hb0/par0
  }
#undef STEP

  // h_512 own half lives in hb0 (step 511 wrote it; loop ended with barrier)
#pragma unroll
  for (int j = 0; j < 8; ++j) {
    const int row = tid >> 5;
    const int col = ownb + (tid & 31) * 8 + j;
    out[(size_t)(pid * 16 + row) * 512 + col] = (float)hb0[row][col ^ ((row & 7) << 3)];
  }
}

// ------------------------------------------------------------------ launch --
extern "C" void kernel_launch(void* const* d_in, const int* in_sizes, int n_in,
                              void* d_out, int out_size, void* d_ws, size_t ws_size,
                              hipStream_t stream) {
  const int*   X    = (const int*)d_in[0];
  const float* emb  = (const float*)d_in[1];
  const float* W_hh = (const float*)d_in[2];
  const float* b_hh = (const float*)d_in[3];
  const float* W_xh = (const float*)d_in[4];
  const float* b_xh = (const float*)d_in[5];
  float* out = (float*)d_out;

  char* ws = (char*)d_ws;
  u16* Whf = (u16*)ws;                          // 512 KB
  u16* Wxf = (u16*)(ws + 524288);               // 256 KB
  u16* xpf = (u16*)(ws + 786432);               // 128 MB
  u16* xch = (u16*)(ws + 786432 + 134217728);   // 512 KB exchange
  int* flg = (int*)(ws + 786432 + 134217728 + 524288);  // 128 B flags

  // reset pair flags every launch (graph-replay safe; stream-ordered)
  hipMemsetAsync(flg, 0, 32 * sizeof(int), stream);

  preconv_kernel<<<128, 256, 0, stream>>>(W_hh, Whf, 512, 1);
  preconv_kernel<<< 64, 256, 0, stream>>>(W_xh, Wxf, 256, 0);
  phaseA_kernel<<<1024, 512, 0, stream>>>(X, emb, Wxf, b_hh, b_xh, xpf);

  void* args[] = {(void*)&Whf, (void*)&xpf, (void*)&xch, (void*)&flg, (void*)&out};
  hipLaunchCooperativeKernel((void*)phaseB_kernel, dim3(32), dim3(512),
                             args, 0, stream);
}

// Round 8
// 2565.837 us; speedup vs baseline: 1.1310x; 1.1310x over previous
//
#include <hip/hip_runtime.h>

// SimpleRNN: VOCAB=32000, EMBED=256, HIDDEN=512, N=256, L=512
// out = h_512 (256x512 f32), h_{t+1} = tanh(h W_hh^T + b_hh + b_xh + emb[X] W_xh^T)
//
// Round-8 = round-6 structure (16 blocks, 1045 us) with W-tail moved LDS -> L2:
//  per CU per step LDS was the binding pipe (256 b128 reads ~3700 cyc); tail
//  kt12..15 now streams from L2-resident Whf on the idle vmem pipe, pipelined
//  >=3 kt ahead of use. LDS = 32 KB static (h dbuf only). Round-7's cross-block
//  exchange reverted (WRITE_SIZE proved exports went through HBM).

typedef _Float16 f16;
typedef f16 f16x8 __attribute__((ext_vector_type(8)));
typedef float f32x4 __attribute__((ext_vector_type(4)));
typedef unsigned short u16;

union U8 { uint4 u; f16x8 h; };
union U4 { uint2 u; f16 h[4]; };

// ---------------------------------------------------------------- preconv ---
// One frag = 64 lanes x 8 f16 (1KB). lane l supplies W[col = c*16 + (l&15)][k = kt*32 + (l>>4)*8 + j].
// mode 0 (W_xh, K=256): f = (w*4+mt)*8 + kt
// mode 1 (W_hh, K=512): kt<12 : f = kt*32 + w*4 + mt        (head, reg-resident)
//                       kt>=12: f = 384 + w*16 + mt*4 + (kt-12)  (tail, per-wave 16KB, L2-read)
__global__ void preconv_kernel(const float* __restrict__ W, u16* __restrict__ dst,
                               int kstride, int mode) {
  int t = blockIdx.x * blockDim.x + threadIdx.x;
  int f = t >> 6, l = t & 63;
  int kt, w, nt;
  if (mode == 0)    { kt = f & 7;  nt = (f >> 3) & 3; w = f >> 5; }
  else if (f < 384) { nt = f & 3;  w = (f >> 2) & 7;  kt = f >> 5; }
  else { int g = f - 384; kt = 12 + (g & 3); nt = (g >> 2) & 3; w = g >> 4; }
  int col = w * 64 + nt * 16 + (l & 15);
  int k   = kt * 32 + (l >> 4) * 8;
  const float* src = W + (size_t)col * kstride + k;
  float4 v0 = *(const float4*)src;
  float4 v1 = *(const float4*)(src + 4);
  U8 r;
  r.h = (f16x8){(f16)v0.x, (f16)v0.y, (f16)v0.z, (f16)v0.w,
                (f16)v1.x, (f16)v1.y, (f16)v1.z, (f16)v1.w};
  *(uint4*)(dst + (size_t)f * 512 + l * 8) = r.u;
}

// ----------------------------------------------------------------- phaseA ---
// Round-6 exact. Grid 1024 = 16 bn x 64 bl. 512 thr, 8 waves.
// Writes xpf[t][cq][n][4] f16, cq = out_col>>2, n = batch row, biases folded.
__global__ __launch_bounds__(512, 2) void phaseA_kernel(
    const int* __restrict__ X, const float* __restrict__ emb,
    const u16* __restrict__ Wxf, const float* __restrict__ b_hh,
    const float* __restrict__ b_xh, u16* __restrict__ xpf) {
  __shared__ f16 A[128 * 256];  // 64 KB
  const int tid = threadIdx.x, w = tid >> 6, l = tid & 63;
  const int b = blockIdx.x, bn = b >> 6, bl = b & 63;
  const int lr = l & 15, lg = l >> 4;

  f16x8 wx[4][8];
#pragma unroll
  for (int mt = 0; mt < 4; ++mt)
#pragma unroll
    for (int kt = 0; kt < 8; ++kt) {
      U8 u; u.u = *(const uint4*)(Wxf + (size_t)((w * 4 + mt) * 8 + kt) * 512 + l * 8);
      wx[mt][kt] = u.h;
    }
  float bias[4][4];
#pragma unroll
  for (int mt = 0; mt < 4; ++mt)
#pragma unroll
    for (int r = 0; r < 4; ++r) {
      int c = w * 64 + mt * 16 + lg * 4 + r;
      bias[mt][r] = b_hh[c] + b_xh[c];
    }

  int xs[16];
  const int lseq = bl * 8 + w;
#pragma unroll
  for (int i = 0; i < 16; ++i) xs[i] = X[(bn * 16 + i) * 512 + lseq];
#pragma unroll
  for (int i = 0; i < 16; ++i) {
    float4 v = *(const float4*)(emb + (size_t)xs[i] * 256 + l * 4);
    U4 p; p.h[0] = (f16)v.x; p.h[1] = (f16)v.y; p.h[2] = (f16)v.z; p.h[3] = (f16)v.w;
    int row = w * 16 + i;
    *(uint2*)(&A[row * 256 + ((l * 4) ^ ((row & 7) << 3))]) = p.u;
  }
  __syncthreads();

#pragma unroll 1
  for (int nt = 0; nt < 8; ++nt) {
    f32x4 acc[4];
#pragma unroll
    for (int mt = 0; mt < 4; ++mt) acc[mt] = (f32x4){0.f, 0.f, 0.f, 0.f};
    const f16* Brow = &A[(nt * 16 + lr) * 256];
    const int sw = (lr & 7) << 3;
#pragma unroll
    for (int kt = 0; kt < 8; ++kt) {
      f16x8 bfr = *(const f16x8*)(Brow + ((kt * 32 + lg * 8) ^ sw));
#pragma unroll
      for (int mt = 0; mt < 4; ++mt)
        acc[mt] = __builtin_amdgcn_mfma_f32_16x16x32_f16(wx[mt][kt], bfr, acc[mt], 0, 0, 0);
    }
    const int t = bl * 8 + nt;
#pragma unroll
    for (int mt = 0; mt < 4; ++mt) {
      U4 p;
#pragma unroll
      for (int r = 0; r < 4; ++r) p.h[r] = (f16)(acc[mt][r] + bias[mt][r]);
      *(uint2*)(xpf + (size_t)t * 131072 + (w * 16 + mt * 4 + lg) * 1024
                    + (bn * 16 + lr) * 4) = p.u;
    }
  }
}

// ----------------------------------------------------------------- phaseB ---
// 16 blocks x 512 thr (8 waves, 2/SIMD). Block bb: batch rows [16bb,16bb+16).
// Wave w: out cols [64w,64w+64). h[16][512] f16 dbuf in static LDS (32 KB),
// storage rule: h[row][col] at u16 idx row*512 + (col ^ ((row&7)<<3)).
// W: kt0..11 reg-resident (192 regs); kt12..15 streamed from L2 per step,
// pipelined: batch loads issued >=3 kt-blocks before consumption.

#define HFRAG(HR, KT) (*(const f16x8*)((HR) + lr * 512 + (((KT) * 32 + lg * 8) ^ asw)))

#define MF_HEAD(HR, KT)                                                           \
  do { f16x8 hf = HFRAG(HR, KT);                                                  \
    _Pragma("unroll")                                                             \
    for (int mt = 0; mt < 4; ++mt)                                                \
      acc[mt] = __builtin_amdgcn_mfma_f32_16x16x32_f16(wa[KT][mt], hf, acc[mt], 0, 0, 0); \
  } while (0)

#define MF_TAIL(HR, KT, TT)                                                       \
  do { f16x8 hf = HFRAG(HR, KT);                                                  \
    _Pragma("unroll")                                                             \
    for (int mt = 0; mt < 4; ++mt)                                                \
      acc[mt] = __builtin_amdgcn_mfma_f32_16x16x32_f16(TT[mt].h, hf, acc[mt], 0, 0, 0); \
  } while (0)

#define TLOAD(TT, KOFF)                                                           \
  do { _Pragma("unroll")                                                          \
    for (int mt = 0; mt < 4; ++mt)                                                \
      TT[mt].u = *(const uint4*)(gt + (size_t)(mt * 4 + (KOFF)) * 512);           \
  } while (0)

#define STEP(T, HR, HW, XPc, XPn)                                                 \
  do {                                                                            \
    { /* prefetch xp for step T+1 (clamped, in-bounds) */                         \
      const int tn = ((T) + 1 < 512) ? ((T) + 1) : 511;                           \
      const u16* p = xpb + (size_t)tn * 131072;                                   \
      _Pragma("unroll")                                                           \
      for (int mt = 0; mt < 4; ++mt) XPn[mt] = *(const uint2*)(p + mt * 4096);    \
    }                                                                             \
    f32x4 acc[4];                                                                 \
    _Pragma("unroll")                                                             \
    for (int mt = 0; mt < 4; ++mt) acc[mt] = (f32x4){0.f, 0.f, 0.f, 0.f};         \
    U8 tA[4], tB[4], tC[4], tD[4];                                                \
    TLOAD(tA, 0);                                                                 \
    MF_HEAD(HR, 0); MF_HEAD(HR, 1); MF_HEAD(HR, 2); MF_HEAD(HR, 3);               \
    TLOAD(tB, 1);                                                                 \
    MF_HEAD(HR, 4); MF_HEAD(HR, 5); MF_HEAD(HR, 6); MF_HEAD(HR, 7);               \
    TLOAD(tC, 2);                                                                 \
    MF_HEAD(HR, 8); MF_HEAD(HR, 9); MF_HEAD(HR, 10); MF_HEAD(HR, 11);             \
    TLOAD(tD, 3);                                                                 \
    MF_TAIL(HR, 12, tA); MF_TAIL(HR, 13, tB);                                     \
    MF_TAIL(HR, 14, tC); MF_TAIL(HR, 15, tD);                                     \
    _Pragma("unroll")                                                             \
    for (int mt = 0; mt < 4; ++mt) {                                              \
      U4 px; px.u = XPc[mt];                                                      \
      U4 o;                                                                       \
      _Pragma("unroll")                                                           \
      for (int r = 0; r < 4; ++r) {                                               \
        float z = acc[mt][r] + (float)px.h[r];                                    \
        float e = __builtin_amdgcn_exp2f(z * 2.885390081777927f);                 \
        o.h[r] = (f16)(1.0f - 2.0f * __builtin_amdgcn_rcpf(e + 1.0f));            \
      }                                                                           \
      *(uint2*)((HW) + lr * 512 + ((w * 64 + mt * 16 + lg * 4) ^ asw)) = o.u;     \
    }                                                                             \
    __syncthreads();                                                              \
  } while (0)

__global__ __launch_bounds__(512)
__attribute__((amdgpu_waves_per_eu(2, 2)))
void phaseB_kernel(const u16* __restrict__ Whf, const u16* __restrict__ xpf,
                   float* __restrict__ out) {
  __shared__ f16 hb0[16 * 512];  // 16 KB (even steps read)
  __shared__ f16 hb1[16 * 512];  // 16 KB
  const int tid = threadIdx.x, w = tid >> 6, l = tid & 63;
  const int bb = blockIdx.x;
  const int lr = l & 15, lg = l >> 4;
  const int asw = (lr & 7) << 3;

  // W head resident: wa[kt][mt], frag f = kt*32 + w*4 + mt  (192 regs)
  f16x8 wa[12][4];
#pragma unroll
  for (int kt = 0; kt < 12; ++kt)
#pragma unroll
    for (int mt = 0; mt < 4; ++mt) {
      U8 u; u.u = *(const uint4*)(Whf + (size_t)(kt * 32 + w * 4 + mt) * 512 + l * 8);
      wa[kt][mt] = u.h;
    }
  { // h0 = 0 (hb1 fully written before first read)
    float* hz = (float*)hb0;
#pragma unroll
    for (int i = 0; i < 8; ++i) hz[i * 512 + tid] = 0.f;
  }
  __syncthreads();

  // invariants: W-tail L2 base (per-wave 16 KB chunk), xp base
  const u16* gt  = Whf + (size_t)(384 + w * 16) * 512 + l * 8;
  const u16* xpb = xpf + (size_t)(w * 16 + lg) * 1024 + (bb * 16 + lr) * 4;

  uint2 xpA[4], xpB[4];
#pragma unroll
  for (int mt = 0; mt < 4; ++mt) xpA[mt] = *(const uint2*)(xpb + mt * 4096);

#pragma unroll 1
  for (int t2 = 0; t2 < 256; ++t2) {
    const int t = t2 * 2;
    STEP(t,     hb0, hb1, xpA, xpB);   // even: read hb0, write hb1
    STEP(t + 1, hb1, hb0, xpB, xpA);   // odd : read hb1, write hb0
  }

  // final h in hb0 (step 511 wrote it; STEP ends with barrier)
#pragma unroll
  for (int i = 0; i < 16; ++i) {
    f16 v = hb0[i * 512 + (tid ^ ((i & 7) << 3))];
    out[(size_t)(bb * 16 + i) * 512 + tid] = (float)v;
  }
}

#undef STEP
#undef TLOAD
#undef MF_TAIL
#undef MF_HEAD
#undef HFRAG

// ------------------------------------------------------------------ launch --
extern "C" void kernel_launch(void* const* d_in, const int* in_sizes, int n_in,
                              void* d_out, int out_size, void* d_ws, size_t ws_size,
                              hipStream_t stream) {
  const int*   X    = (const int*)d_in[0];
  const float* emb  = (const float*)d_in[1];
  const float* W_hh = (const float*)d_in[2];
  const float* b_hh = (const float*)d_in[3];
  const float* W_xh = (const float*)d_in[4];
  const float* b_xh = (const float*)d_in[5];
  float* out = (float*)d_out;

  char* ws = (char*)d_ws;
  u16* Whf = (u16*)ws;                    // 512 KB
  u16* Wxf = (u16*)(ws + 524288);         // 256 KB
  u16* xpf = (u16*)(ws + 786432);         // 128 MB

  preconv_kernel<<<128, 256, 0, stream>>>(W_hh, Whf, 512, 1);
  preconv_kernel<<< 64, 256, 0, stream>>>(W_xh, Wxf, 256, 0);
  phaseA_kernel<<<1024, 512, 0, stream>>>(X, emb, Wxf, b_hh, b_xh, xpf);
  phaseB_kernel<<<16, 512, 0, stream>>>(Whf, xpf, out);
}

// Round 9
// 2020.162 us; speedup vs baseline: 1.4364x; 1.2701x over previous
//
#include <hip/hip_runtime.h>

// SimpleRNN: VOCAB=32000, EMBED=256, HIDDEN=512, N=256, L=512
// out = h_512 (256x512 f32), h_{t+1} = tanh(h W_hh^T + b_hh + b_xh + emb[X] W_xh^T)
//
// Round-9: 16 blocks x 256 thr (4 waves, 1 wave/SIMD -> 512-reg unified budget).
//  Wave w owns out cols [128w,128w+128) (mt=0..7).
//  W_hh kt0..11: 384 regs resident. kt12..15: 128 KB LDS, static-offset ds_reads.
//  h[16][512] f16 dbuf (32 KB) XOR-swizzled; 1 barrier/step; xp loaded at step
//  top (MFMA section covers HBM latency; no dbuf regs).
//  Round-8's L2-tail streaming reverted: it spilled (WRITE_SIZE 10MB proved it).

typedef _Float16 f16;
typedef f16 f16x8 __attribute__((ext_vector_type(8)));
typedef float f32x4 __attribute__((ext_vector_type(4)));
typedef unsigned short u16;

union U8 { uint4 u; f16x8 h; };
union U4 { uint2 u; f16 h[4]; };

// ---------------------------------------------------------------- preconv ---
// One frag = 64 lanes x 8 f16 (1KB). lane l supplies W[col = c16*16 + (l&15)][k = kt*32 + (l>>4)*8 + j].
// mode 0 (W_xh, K=256): f = c16*8 + kt   (c16 = f>>3, kt = f&7)   [phaseA layout, known-good]
// mode 1 (W_hh, K=512): f = c16*16 + kt  (c16 = f>>4, kt = f&15)  [col-tile-major]
__global__ void preconv_kernel(const float* __restrict__ W, u16* __restrict__ dst,
                               int kstride, int mode) {
  int t = blockIdx.x * blockDim.x + threadIdx.x;
  int f = t >> 6, l = t & 63;
  int kt, c16;
  if (mode == 0) { kt = f & 7;  c16 = f >> 3; }
  else           { kt = f & 15; c16 = f >> 4; }
  int col = c16 * 16 + (l & 15);
  int k   = kt * 32 + (l >> 4) * 8;
  const float* src = W + (size_t)col * kstride + k;
  float4 v0 = *(const float4*)src;
  float4 v1 = *(const float4*)(src + 4);
  U8 r;
  r.h = (f16x8){(f16)v0.x, (f16)v0.y, (f16)v0.z, (f16)v0.w,
                (f16)v1.x, (f16)v1.y, (f16)v1.z, (f16)v1.w};
  *(uint4*)(dst + (size_t)f * 512 + l * 8) = r.u;
}

// ----------------------------------------------------------------- phaseA ---
// Round-6 exact (known-good). Grid 1024 = 16 bn x 64 bl. 512 thr, 8 waves.
// Writes xpf[t][cq][n][4] f16, cq = out_col>>2 (0..127), n = batch row, biases folded.
__global__ __launch_bounds__(512, 2) void phaseA_kernel(
    const int* __restrict__ X, const float* __restrict__ emb,
    const u16* __restrict__ Wxf, const float* __restrict__ b_hh,
    const float* __restrict__ b_xh, u16* __restrict__ xpf) {
  __shared__ f16 A[128 * 256];  // 64 KB
  const int tid = threadIdx.x, w = tid >> 6, l = tid & 63;
  const int b = blockIdx.x, bn = b >> 6, bl = b & 63;
  const int lr = l & 15, lg = l >> 4;

  f16x8 wx[4][8];
#pragma unroll
  for (int mt = 0; mt < 4; ++mt)
#pragma unroll
    for (int kt = 0; kt < 8; ++kt) {
      U8 u; u.u = *(const uint4*)(Wxf + (size_t)((w * 4 + mt) * 8 + kt) * 512 + l * 8);
      wx[mt][kt] = u.h;
    }
  float bias[4][4];
#pragma unroll
  for (int mt = 0; mt < 4; ++mt)
#pragma unroll
    for (int r = 0; r < 4; ++r) {
      int c = w * 64 + mt * 16 + lg * 4 + r;
      bias[mt][r] = b_hh[c] + b_xh[c];
    }

  int xs[16];
  const int lseq = bl * 8 + w;
#pragma unroll
  for (int i = 0; i < 16; ++i) xs[i] = X[(bn * 16 + i) * 512 + lseq];
#pragma unroll
  for (int i = 0; i < 16; ++i) {
    float4 v = *(const float4*)(emb + (size_t)xs[i] * 256 + l * 4);
    U4 p; p.h[0] = (f16)v.x; p.h[1] = (f16)v.y; p.h[2] = (f16)v.z; p.h[3] = (f16)v.w;
    int row = w * 16 + i;
    *(uint2*)(&A[row * 256 + ((l * 4) ^ ((row & 7) << 3))]) = p.u;
  }
  __syncthreads();

#pragma unroll 1
  for (int nt = 0; nt < 8; ++nt) {
    f32x4 acc[4];
#pragma unroll
    for (int mt = 0; mt < 4; ++mt) acc[mt] = (f32x4){0.f, 0.f, 0.f, 0.f};
    const f16* Brow = &A[(nt * 16 + lr) * 256];
    const int sw = (lr & 7) << 3;
#pragma unroll
    for (int kt = 0; kt < 8; ++kt) {
      f16x8 bfr = *(const f16x8*)(Brow + ((kt * 32 + lg * 8) ^ sw));
#pragma unroll
      for (int mt = 0; mt < 4; ++mt)
        acc[mt] = __builtin_amdgcn_mfma_f32_16x16x32_f16(wx[mt][kt], bfr, acc[mt], 0, 0, 0);
    }
    const int t = bl * 8 + nt;
#pragma unroll
    for (int mt = 0; mt < 4; ++mt) {
      U4 p;
#pragma unroll
      for (int r = 0; r < 4; ++r) p.h[r] = (f16)(acc[mt][r] + bias[mt][r]);
      *(uint2*)(xpf + (size_t)t * 131072 + (w * 16 + mt * 4 + lg) * 1024
                    + (bn * 16 + lr) * 4) = p.u;
    }
  }
}

// ----------------------------------------------------------------- phaseB ---
// 16 blocks x 256 thr (4 waves, 1/SIMD). Block bb: batch rows [16bb,16bb+16).
// Wave w: out cols [128w,128w+128), mt=0..7. h storage rule:
// h[row=batch][col] at u16 idx row*512 + (col ^ ((row&7)<<3)).

#define HFRAG(HR, KT) (*(const f16x8*)((HR) + lr * 512 + (((KT) * 32 + lg * 8) ^ asw)))

#define STEP(T, HR, HW)                                                           \
  do {                                                                            \
    /* xp loads for this step; ~2500 cyc of MFMA below covers HBM latency */      \
    uint2 xp[8];                                                                  \
    {                                                                             \
      const u16* p = xpb + (size_t)(T) * 131072;                                  \
      _Pragma("unroll")                                                           \
      for (int mt = 0; mt < 8; ++mt) xp[mt] = *(const uint2*)(p + mt * 4096);     \
    }                                                                             \
    f32x4 acc[8];                                                                 \
    _Pragma("unroll")                                                             \
    for (int mt = 0; mt < 8; ++mt) acc[mt] = (f32x4){0.f, 0.f, 0.f, 0.f};         \
    _Pragma("unroll")                                                             \
    for (int kt = 0; kt < 12; ++kt) {   /* head: W resident */                    \
      f16x8 hf = HFRAG(HR, kt);                                                   \
      _Pragma("unroll")                                                           \
      for (int mt = 0; mt < 8; ++mt)                                              \
        acc[mt] = __builtin_amdgcn_mfma_f32_16x16x32_f16(wa[kt][mt], hf, acc[mt], 0, 0, 0); \
    }                                                                             \
    _Pragma("unroll")                                                             \
    for (int kt = 12; kt < 16; ++kt) {  /* tail: W from LDS, static offsets */    \
      f16x8 hf = HFRAG(HR, kt);                                                   \
      _Pragma("unroll")                                                           \
      for (int mt = 0; mt < 8; ++mt) {                                            \
        U8 u; u.u = *(const uint4*)(wt + (mt * 4 + (kt - 12)) * 512);             \
        acc[mt] = __builtin_amdgcn_mfma_f32_16x16x32_f16(u.h, hf, acc[mt], 0, 0, 0); \
      }                                                                           \
    }                                                                             \
    _Pragma("unroll")                                                             \
    for (int mt = 0; mt < 8; ++mt) {                                              \
      U4 px; px.u = xp[mt];                                                       \
      U4 o;                                                                       \
      _Pragma("unroll")                                                           \
      for (int r = 0; r < 4; ++r) {                                               \
        float z = acc[mt][r] + (float)px.h[r];                                    \
        float e = __builtin_amdgcn_exp2f(z * 2.885390081777927f);                 \
        o.h[r] = (f16)(1.0f - 2.0f * __builtin_amdgcn_rcpf(e + 1.0f));            \
      }                                                                           \
      *(uint2*)((HW) + lr * 512 + ((w * 128 + mt * 16 + lg * 4) ^ asw)) = o.u;    \
    }                                                                             \
    __syncthreads();                                                              \
  } while (0)

__global__ __launch_bounds__(256, 1)
void phaseB_kernel(const u16* __restrict__ Whf, const u16* __restrict__ xpf,
                   float* __restrict__ out) {
  extern __shared__ char smem[];
  f16* hb0 = (f16*)smem;                   // 16 KB (even steps read)
  f16* hb1 = (f16*)(smem + 16 * 1024);     // 16 KB
  u16* wl  = (u16*)(smem + 32 * 1024);     // 128 KB: W tail, slot s = c16*4+(kt-12)
  const int tid = threadIdx.x, w = tid >> 6, l = tid & 63;
  const int bb = blockIdx.x;
  const int lr = l & 15, lg = l >> 4;
  const int asw = (lr & 7) << 3;

  // W head resident: wa[kt][mt], frag f = (w*8+mt)*16 + kt  (384 regs)
  f16x8 wa[12][8];
#pragma unroll
  for (int kt = 0; kt < 12; ++kt)
#pragma unroll
    for (int mt = 0; mt < 8; ++mt) {
      U8 u; u.u = *(const uint4*)(Whf + (size_t)((w * 8 + mt) * 16 + kt) * 512 + l * 8);
      wa[kt][mt] = u.h;
    }
  // W tail -> LDS: slot s (0..127): c16 = s>>2, kt = 12+(s&3), f = (s>>2)*16 + 12 + (s&3)
#pragma unroll 1
  for (int it = 0; it < 32; ++it) {
    const int s = it * 4 + (tid >> 6);
    const int f = (s >> 2) * 16 + 12 + (s & 3);
    ((uint4*)wl)[s * 64 + (tid & 63)] =
        *(const uint4*)(Whf + (size_t)f * 512 + (tid & 63) * 8);
  }
  { // h0 = 0 (hb1 fully written before first read)
    float* hz = (float*)hb0;
#pragma unroll
    for (int i = 0; i < 16; ++i) hz[i * 256 + tid] = 0.f;
  }
  __syncthreads();

  // invariants: tail LDS base (per-wave 32 KB chunk), xp base
  const u16* wt  = wl + w * 16384 + l * 8;   // + (mt*4 + kt-12)*512, all static imm
  const u16* xpb = xpf + (size_t)(w * 32 + lg) * 1024 + (bb * 16 + lr) * 4;

#pragma unroll 1
  for (int t2 = 0; t2 < 256; ++t2) {
    const int t = t2 * 2;
    STEP(t,     hb0, hb1);   // even: read hb0, write hb1
    STEP(t + 1, hb1, hb0);   // odd : read hb1, write hb0
  }

  // final h in hb0 (step 511 wrote it; STEP ends with barrier)
#pragma unroll
  for (int i = 0; i < 32; ++i) {
    const int row = i >> 1;
    const int col = (i & 1) * 256 + tid;
    out[(size_t)(bb * 16 + row) * 512 + col] = (float)hb0[row * 512 + (col ^ ((row & 7) << 3))];
  }
}

#undef STEP
#undef HFRAG

// ------------------------------------------------------------------ launch --
extern "C" void kernel_launch(void* const* d_in, const int* in_sizes, int n_in,
                              void* d_out, int out_size, void* d_ws, size_t ws_size,
                              hipStream_t stream) {
  const int*   X    = (const int*)d_in[0];
  const float* emb  = (const float*)d_in[1];
  const float* W_hh = (const float*)d_in[2];
  const float* b_hh = (const float*)d_in[3];
  const float* W_xh = (const float*)d_in[4];
  const float* b_xh = (const float*)d_in[5];
  float* out = (float*)d_out;

  char* ws = (char*)d_ws;
  u16* Whf = (u16*)ws;                    // 512 KB
  u16* Wxf = (u16*)(ws + 524288);         // 256 KB
  u16* xpf = (u16*)(ws + 786432);         // 128 MB

  hipFuncSetAttribute((const void*)phaseB_kernel,
                      hipFuncAttributeMaxDynamicSharedMemorySize, 163840);

  preconv_kernel<<<128, 256, 0, stream>>>(W_hh, Whf, 512, 1);
  preconv_kernel<<< 64, 256, 0, stream>>>(W_xh, Wxf, 256, 0);
  phaseA_kernel<<<1024, 512, 0, stream>>>(X, emb, Wxf, b_hh, b_xh, xpf);
  phaseB_kernel<<<16, 256, 163840, stream>>>(Whf, xpf, out);
}